// Round 1
// baseline (2035.926 us; speedup 1.0000x reference)
//
#include <hip/hip_runtime.h>

#define NN 50000
#define EE 800000
#define TT 1000000
#define QQ 1000000
#define GG 4096
#define HID 128
#define NH 8
#define DH 16
#define CHUNK 128

__device__ __forceinline__ float eluf(float x){ return x > 0.f ? x : expm1f(x); }

// ---------------- CSR build ----------------
__global__ void k_count(const int* __restrict__ dst, int m, int* __restrict__ cnt){
  int i = blockIdx.x*blockDim.x + threadIdx.x;
  if (i < m) atomicAdd(&cnt[dst[i]], 1);
}

__global__ void k_scan(const int* __restrict__ cnt, int* __restrict__ off, int n){
  __shared__ int part[1024];
  int t = threadIdx.x;
  int chunk = (n + 1023) >> 10;
  int s0 = t*chunk, s1 = min(n, s0+chunk);
  int sum = 0;
  for (int i=s0;i<s1;i++) sum += cnt[i];
  part[t] = sum;
  __syncthreads();
  for (int d=1; d<1024; d<<=1){
    int v = (t>=d) ? part[t-d] : 0;
    __syncthreads();
    part[t] += v;
    __syncthreads();
  }
  int run = (t==0) ? 0 : part[t-1];
  for (int i=s0;i<s1;i++){ off[i]=run; run += cnt[i]; }
  if (t==0) off[n] = part[1023];
}

__global__ void k_copy_int(const int* __restrict__ a, int* __restrict__ b, int n){
  int i = blockIdx.x*blockDim.x+threadIdx.x;
  if (i<n) b[i]=a[i];
}

__global__ void k_fill(const int* __restrict__ dst, int m, int* __restrict__ cur, int* __restrict__ eid){
  int i = blockIdx.x*blockDim.x+threadIdx.x;
  if (i<m){ int p = atomicAdd(&cur[dst[i]],1); eid[p]=i; }
}

// ---------------- geometry ----------------
__global__ void k_geom_edge(const float* __restrict__ pos, const int* __restrict__ ei, float* __restrict__ d){
  int m = blockIdx.x*blockDim.x+threadIdx.x;
  if (m >= EE) return;
  int i0 = ei[m], i1 = ei[EE+m];
  float dx = pos[i0*3+0]-pos[i1*3+0]+1e-8f;
  float dy = pos[i0*3+1]-pos[i1*3+1]+1e-8f;
  float dz = pos[i0*3+2]-pos[i1*3+2]+1e-8f;
  d[m] = sqrtf(dx*dx+dy*dy+dz*dz);
}

__global__ void k_geom_tri(const float* __restrict__ pos, const int* __restrict__ ti, float* __restrict__ cosa){
  int m = blockIdx.x*blockDim.x+threadIdx.x;
  if (m >= TT) return;
  int i = ti[m], j = ti[TT+m], k = ti[2*TT+m];
  float ux = pos[i*3+0]-pos[j*3+0], uy = pos[i*3+1]-pos[j*3+1], uz = pos[i*3+2]-pos[j*3+2];
  float vx = pos[k*3+0]-pos[j*3+0], vy = pos[k*3+1]-pos[j*3+1], vz = pos[k*3+2]-pos[j*3+2];
  float num = ux*vx+uy*vy+uz*vz;
  float den = sqrtf(ux*ux+uy*uy+uz*uz)*sqrtf(vx*vx+vy*vy+vz*vz) + 1e-8f;
  cosa[m] = num/den;
}

__global__ void k_geom_quad(const float* __restrict__ pos, const int* __restrict__ qi, float* __restrict__ cosd){
  int m = blockIdx.x*blockDim.x+threadIdx.x;
  if (m >= QQ) return;
  int p0 = qi[m], p1 = qi[QQ+m], p2 = qi[2*QQ+m], p3 = qi[3*QQ+m];
  float b1x = pos[p1*3+0]-pos[p0*3+0], b1y = pos[p1*3+1]-pos[p0*3+1], b1z = pos[p1*3+2]-pos[p0*3+2];
  float b2x = pos[p2*3+0]-pos[p1*3+0], b2y = pos[p2*3+1]-pos[p1*3+1], b2z = pos[p2*3+2]-pos[p1*3+2];
  float b3x = pos[p3*3+0]-pos[p2*3+0], b3y = pos[p3*3+1]-pos[p2*3+1], b3z = pos[p3*3+2]-pos[p2*3+2];
  float n1x = b1y*b2z - b1z*b2y, n1y = b1z*b2x - b1x*b2z, n1z = b1x*b2y - b1y*b2x;
  float n2x = b2y*b3z - b2z*b3y, n2y = b2z*b3x - b2x*b3z, n2z = b2x*b3y - b2y*b3x;
  float num = n1x*n2x+n1y*n2y+n1z*n2z;
  float den = sqrtf(n1x*n1x+n1y*n1y+n1z*n1z)*sqrtf(n2x*n2x+n2y*n2y+n2z*n2z) + 1e-8f;
  cosd[m] = num/den;
}

// ---------------- GEMM hl = A @ W  (A: [n,128], W: [128,128]) ----------------
#define GR 16
__global__ __launch_bounds__(128) void k_gemm(const float* __restrict__ A, const float* __restrict__ W,
                                              float* __restrict__ B, int nrows){
  __shared__ float At[GR][HID];
  int col = threadIdx.x;
  for (int r0 = blockIdx.x*GR; r0 < nrows; r0 += gridDim.x*GR){
    int rmax = min(GR, nrows - r0);
    for (int i = threadIdx.x; i < rmax*HID; i += 128) At[i>>7][i&127] = A[(size_t)r0*HID + i];
    __syncthreads();
    float acc[GR];
    #pragma unroll
    for (int r=0;r<GR;r++) acc[r]=0.f;
    for (int k=0;k<HID;k++){
      float w = W[k*HID+col];
      #pragma unroll
      for (int r=0;r<GR;r++) acc[r] = fmaf(At[r][k], w, acc[r]);
    }
    for (int r=0;r<rmax;r++) B[(size_t)(r0+r)*HID+col] = acc[r];
    __syncthreads();
  }
}

// ---------------- per-node attention projections for the 3 hop types ----------------
__global__ void k_proj(const float* __restrict__ hl,
                       const float* __restrict__ ae, const float* __restrict__ at, const float* __restrict__ aq,
                       float* __restrict__ qa_e, float* __restrict__ ka_e,
                       float* __restrict__ qa_t, float* __restrict__ ka_t,
                       float* __restrict__ qa_q, float* __restrict__ ka_q){
  int i = blockIdx.x*blockDim.x + threadIdx.x;  // n*8+h
  if (i >= NN*NH) return;
  int h = i & 7; int n = i >> 3;
  const float* v = hl + (size_t)n*HID + h*DH;
  float x[DH];
  #pragma unroll
  for (int d=0; d<DH; d++) x[d] = v[d];
  const float* Ae = ae + h*33; const float* At_ = at + h*33; const float* Aq = aq + h*33;
  float s0=0,s1=0,s2=0,s3=0,s4=0,s5=0;
  #pragma unroll
  for (int d=0; d<DH; d++){
    s0 = fmaf(x[d], Ae[d],      s0);  s1 = fmaf(x[d], Ae[DH+d],  s1);
    s2 = fmaf(x[d], At_[d],     s2);  s3 = fmaf(x[d], At_[DH+d], s3);
    s4 = fmaf(x[d], Aq[d],      s4);  s5 = fmaf(x[d], Aq[DH+d],  s5);
  }
  qa_e[i]=s0; ka_e[i]=s1; qa_t[i]=s2; ka_t[i]=s3; qa_q[i]=s4; ka_q[i]=s5;
}

// ---------------- edge bias: edge_attr @ We[l]  ([E,16]x[16,8]) ----------------
__global__ void k_bias(const float* __restrict__ ea, const float* __restrict__ Wel, float* __restrict__ bias){
  int m = blockIdx.x*blockDim.x+threadIdx.x;
  if (m >= EE) return;
  float a[16];
  #pragma unroll
  for (int c=0;c<16;c++) a[c] = ea[(size_t)m*16+c];
  #pragma unroll
  for (int h=0;h<NH;h++){
    float s = 0.f;
    #pragma unroll
    for (int c=0;c<16;c++) s = fmaf(a[c], Wel[c*NH+h], s);
    bias[(size_t)m*NH+h] = s;
  }
}

// ---------------- fused hop: softmax over incoming edges + aggregation ----------------
// one block (128 threads) per destination node; thread t owns output dim t (head = t>>4)
__global__ __launch_bounds__(128) void k_hop(
    const int* __restrict__ off, const int* __restrict__ eid, const int* __restrict__ srcarr,
    const float* __restrict__ qa, const float* __restrict__ ka,
    const float* __restrict__ geom, const float* __restrict__ bias,
    const float* __restrict__ al,  // a[l] base [8][33]; coef = al[h*33+32]
    const float* __restrict__ hh, float* __restrict__ agg, int addmode){
  __shared__ float sh_e[CHUNK*NH];
  __shared__ float sh_geom[CHUNK];
  __shared__ int   sh_src[CHUNK];
  __shared__ int   sh_eid[CHUNK];
  __shared__ float sh_s[NH];
  __shared__ float sh_coef[NH];
  __shared__ float sh_qa[NH];
  int n = blockIdx.x;
  int t = threadIdx.x;
  int start = off[n];
  int deg = off[n+1] - start;
  if (t < NH){ sh_s[t]=0.f; sh_coef[t]=al[t*33+32]; sh_qa[t]=qa[n*NH+t]; }
  __syncthreads();
  int ht = t >> 4;
  float acc = 0.f;
  if (deg > 0){
    bool onechunk = (deg <= CHUNK);
    // pass A: denominators (cache e if it fits)
    for (int base=0; base<deg; base+=CHUNK){
      int cd = min(CHUNK, deg-base);
      if (t < cd){
        int me = eid[start+base+t];
        sh_eid[t]=me; sh_src[t]=srcarr[me]; sh_geom[t]=geom[me];
      }
      __syncthreads();
      for (int i=t; i<cd*NH; i+=128){
        int m = i>>3, h = i&7;
        float lg = sh_qa[h] + ka[sh_src[m]*NH+h] + sh_geom[m]*sh_coef[h];
        if (bias) lg += bias[(size_t)sh_eid[m]*NH + h];
        lg = lg>=0.f ? lg : 0.2f*lg;
        float e = __expf(lg);
        if (onechunk) sh_e[i] = e;
        atomicAdd(&sh_s[h], e);
      }
      __syncthreads();
    }
    float sinv = 1.f/(sh_s[ht] + 1e-16f);
    // pass B: weighted aggregation into registers
    if (onechunk){
      for (int m=0;m<deg;m++){
        float alpha = sh_e[m*NH+ht]*sinv;
        acc = fmaf(hh[(size_t)sh_src[m]*HID + t], alpha, acc);
      }
    } else {
      for (int base=0; base<deg; base+=CHUNK){
        int cd = min(CHUNK, deg-base);
        __syncthreads();
        if (t < cd){
          int me = eid[start+base+t];
          sh_eid[t]=me; sh_src[t]=srcarr[me]; sh_geom[t]=geom[me];
        }
        __syncthreads();
        for (int i=t;i<cd*NH;i+=128){
          int m=i>>3, h=i&7;
          float lg = sh_qa[h] + ka[sh_src[m]*NH+h] + sh_geom[m]*sh_coef[h];
          if (bias) lg += bias[(size_t)sh_eid[m]*NH+h];
          lg = lg>=0.f ? lg : 0.2f*lg;
          sh_e[i] = __expf(lg);
        }
        __syncthreads();
        for (int m=0;m<cd;m++){
          float alpha = sh_e[m*NH+ht]*sinv;
          acc = fmaf(hh[(size_t)sh_src[m]*HID + t], alpha, acc);
        }
      }
    }
  }
  size_t oi = (size_t)n*HID + t;
  if (addmode) agg[oi] += acc; else agg[oi] = acc;
}

// ---------------- h = elu(hl + agg) ----------------
__global__ void k_elu(const float* __restrict__ hl, const float* __restrict__ agg, float* __restrict__ h, int total){
  int i = blockIdx.x*blockDim.x+threadIdx.x;
  if (i < total){ float v = hl[i]+agg[i]; h[i] = eluf(v); }
}

// ---------------- graph offsets (batch is sorted) ----------------
__global__ void k_graph_offsets(const int* __restrict__ batch, int* __restrict__ goff){
  int g = blockIdx.x*blockDim.x+threadIdx.x;
  if (g > GG) return;
  int lo = 0, hi = NN;
  while (lo < hi){ int mid = (lo+hi)>>1; if (batch[mid] < g) lo = mid+1; else hi = mid; }
  goff[g] = lo;
}

// ---------------- pooling: sum + max per graph ----------------
__global__ __launch_bounds__(128) void k_pool(const float* __restrict__ h, const int* __restrict__ goff,
                                              float* __restrict__ gs, float* __restrict__ gmx){
  int g = blockIdx.x, t = threadIdx.x;
  int s = goff[g], e = goff[g+1];
  float sum = 0.f, mx = -INFINITY;
  for (int n=s; n<e; n++){
    float v = h[(size_t)n*HID+t];
    sum += v; mx = fmaxf(mx, v);
  }
  gs[(size_t)g*HID+t] = sum;
  gmx[(size_t)g*HID+t] = (s < e) ? mx : 0.f;
}

// ---------------- readout MLP: [257]->256->256->1, one block per graph ----------------
__global__ __launch_bounds__(256) void k_mlp(const float* __restrict__ gs, const float* __restrict__ gmx,
    const float* __restrict__ temps,
    const float* __restrict__ W1, const float* __restrict__ b1,
    const float* __restrict__ W2, const float* __restrict__ b2,
    const float* __restrict__ W3, const float* __restrict__ b3,
    float* __restrict__ out){
  __shared__ float mol[257];
  __shared__ float hd[256];
  __shared__ float red[256];
  int g = blockIdx.x, t = threadIdx.x;
  if (t < 128){ mol[t] = gs[(size_t)g*HID+t]; mol[128+t] = gmx[(size_t)g*HID+t]; }
  if (t == 0) mol[256] = temps[g];
  __syncthreads();
  float acc = b1[t];
  for (int k=0;k<257;k++) acc = fmaf(mol[k], W1[k*256+t], acc);
  hd[t] = eluf(acc);
  __syncthreads();
  acc = b2[t];
  for (int k=0;k<256;k++) acc = fmaf(hd[k], W2[k*256+t], acc);
  red[t] = eluf(acc) * W3[t];
  __syncthreads();
  for (int s=128;s>0;s>>=1){ if (t < s) red[t] += red[t+s]; __syncthreads(); }
  if (t == 0) out[g] = red[0] + b3[0];
}

extern "C" void kernel_launch(void* const* d_in, const int* in_sizes, int n_in,
                              void* d_out, int out_size, void* d_ws, size_t ws_size,
                              hipStream_t stream){
  const float* x         = (const float*)d_in[0];
  const float* pos       = (const float*)d_in[1];
  const float* edge_attr = (const float*)d_in[2];
  const float* temps     = (const float*)d_in[3];
  const int*   ei        = (const int*)d_in[4];
  const int*   ti        = (const int*)d_in[5];
  const int*   qi        = (const int*)d_in[6];
  const int*   batch     = (const int*)d_in[7];
  const float* W         = (const float*)d_in[8];
  const float* a_e       = (const float*)d_in[9];
  const float* a_t       = (const float*)d_in[10];
  const float* a_q       = (const float*)d_in[11];
  const float* We        = (const float*)d_in[12];
  const float* W1        = (const float*)d_in[13];
  const float* b1        = (const float*)d_in[14];
  const float* W2        = (const float*)d_in[15];
  const float* b2        = (const float*)d_in[16];
  const float* W3        = (const float*)d_in[17];
  const float* b3        = (const float*)d_in[18];
  float* out = (float*)d_out;

  char* base = (char*)d_ws; size_t woff = 0;
  auto alloc = [&](size_t bytes)->void*{
    void* p = base + woff;
    woff = (woff + bytes + 255) & ~(size_t)255;
    return p;
  };
  float* hbuf  = (float*)alloc((size_t)NN*HID*4);
  float* hl    = (float*)alloc((size_t)NN*HID*4);
  float* agg   = (float*)alloc((size_t)NN*HID*4);
  float* qa_e  = (float*)alloc((size_t)NN*NH*4);
  float* ka_e  = (float*)alloc((size_t)NN*NH*4);
  float* qa_t  = (float*)alloc((size_t)NN*NH*4);
  float* ka_t  = (float*)alloc((size_t)NN*NH*4);
  float* qa_q  = (float*)alloc((size_t)NN*NH*4);
  float* ka_q  = (float*)alloc((size_t)NN*NH*4);
  float* dgeom = (float*)alloc((size_t)EE*4);
  float* cosa  = (float*)alloc((size_t)TT*4);
  float* cosd  = (float*)alloc((size_t)QQ*4);
  float* biasE = (float*)alloc((size_t)EE*NH*4);
  float* gs    = (float*)alloc((size_t)GG*HID*4);
  float* gmx   = (float*)alloc((size_t)GG*HID*4);
  int* cnt     = (int*)alloc((size_t)3*NN*4);
  int* off_e   = (int*)alloc((size_t)(NN+1)*4);
  int* off_t   = (int*)alloc((size_t)(NN+1)*4);
  int* off_q   = (int*)alloc((size_t)(NN+1)*4);
  int* cur_e   = (int*)alloc((size_t)NN*4);
  int* cur_t   = (int*)alloc((size_t)NN*4);
  int* cur_q   = (int*)alloc((size_t)NN*4);
  int* eid_e   = (int*)alloc((size_t)EE*4);
  int* eid_t   = (int*)alloc((size_t)TT*4);
  int* eid_q   = (int*)alloc((size_t)QQ*4);
  int* goff    = (int*)alloc((size_t)(GG+1)*4);

  // ---- CSR build (dst rows: ei[0:E], ti[0:T], qi[0:Q]) ----
  hipMemsetAsync(cnt, 0, (size_t)3*NN*4, stream);
  k_count<<<(EE+255)/256,256,0,stream>>>(ei, EE, cnt);
  k_count<<<(TT+255)/256,256,0,stream>>>(ti, TT, cnt+NN);
  k_count<<<(QQ+255)/256,256,0,stream>>>(qi, QQ, cnt+2*NN);
  k_scan<<<1,1024,0,stream>>>(cnt,      off_e, NN);
  k_scan<<<1,1024,0,stream>>>(cnt+NN,   off_t, NN);
  k_scan<<<1,1024,0,stream>>>(cnt+2*NN, off_q, NN);
  k_copy_int<<<(NN+255)/256,256,0,stream>>>(off_e, cur_e, NN);
  k_copy_int<<<(NN+255)/256,256,0,stream>>>(off_t, cur_t, NN);
  k_copy_int<<<(NN+255)/256,256,0,stream>>>(off_q, cur_q, NN);
  k_fill<<<(EE+255)/256,256,0,stream>>>(ei, EE, cur_e, eid_e);
  k_fill<<<(TT+255)/256,256,0,stream>>>(ti, TT, cur_t, eid_t);
  k_fill<<<(QQ+255)/256,256,0,stream>>>(qi, QQ, cur_q, eid_q);

  // ---- geometry ----
  k_geom_edge<<<(EE+255)/256,256,0,stream>>>(pos, ei, dgeom);
  k_geom_tri <<<(TT+255)/256,256,0,stream>>>(pos, ti, cosa);
  k_geom_quad<<<(QQ+255)/256,256,0,stream>>>(pos, qi, cosd);
  k_graph_offsets<<<(GG+1+255)/256,256,0,stream>>>(batch, goff);

  // ---- layers ----
  for (int l=0; l<3; l++){
    const float* hin = (l==0) ? x : hbuf;
    k_gemm<<<3125,128,0,stream>>>(hin, W + (size_t)l*HID*HID, hl, NN);
    k_proj<<<(NN*NH+255)/256,256,0,stream>>>(hl, a_e+l*264, a_t+l*264, a_q+l*264,
                                             qa_e, ka_e, qa_t, ka_t, qa_q, ka_q);
    k_bias<<<(EE+255)/256,256,0,stream>>>(edge_attr, We + l*DH*NH, biasE);
    k_hop<<<NN,128,0,stream>>>(off_e, eid_e, ei+EE,   qa_e, ka_e, dgeom, biasE,  a_e+l*264, hl, agg, 0);
    k_hop<<<NN,128,0,stream>>>(off_t, eid_t, ti+2*TT, qa_t, ka_t, cosa,  nullptr, a_t+l*264, hl, agg, 1);
    k_hop<<<NN,128,0,stream>>>(off_q, eid_q, qi+3*QQ, qa_q, ka_q, cosd,  nullptr, a_q+l*264, hl, agg, 1);
    k_elu<<<(NN*HID+255)/256,256,0,stream>>>(hl, agg, hbuf, NN*HID);
  }

  // ---- readout ----
  k_pool<<<GG,128,0,stream>>>(hbuf, goff, gs, gmx);
  k_mlp<<<GG,256,0,stream>>>(gs, gmx, temps, W1, b1, W2, b2, W3, b3, out);
}

// Round 2
// 1635.987 us; speedup vs baseline: 1.2445x; 1.2445x over previous
//
#include <hip/hip_runtime.h>
#include <hip/hip_fp16.h>

#define NN 50000
#define EE 800000
#define TT 1000000
#define QQ 1000000
#define GG 4096
#define HID 128
#define NH 8
#define DH 16
#define CHUNK 128

__device__ __forceinline__ float eluf(float x){ return x > 0.f ? x : expm1f(x); }

// ---------------- CSR build ----------------
__global__ void k_count(const int* __restrict__ dst, int m, int* __restrict__ cnt){
  int i = blockIdx.x*blockDim.x + threadIdx.x;
  if (i < m) atomicAdd(&cnt[dst[i]], 1);
}

// 3 independent exclusive scans in one launch (blockIdx.x selects the array)
__global__ __launch_bounds__(1024) void k_scan3(const int* __restrict__ cnt, int* __restrict__ off_e,
                                                int* __restrict__ off_t, int* __restrict__ off_q, int n){
  __shared__ int part[1024];
  const int* c = cnt + blockIdx.x*n;
  int* off = (blockIdx.x==0) ? off_e : (blockIdx.x==1) ? off_t : off_q;
  int t = threadIdx.x;
  int chunk = (n + 1023) >> 10;
  int s0 = t*chunk, s1 = min(n, s0+chunk);
  int sum = 0;
  for (int i=s0;i<s1;i++) sum += c[i];
  part[t] = sum;
  __syncthreads();
  for (int d=1; d<1024; d<<=1){
    int v = (t>=d) ? part[t-d] : 0;
    __syncthreads();
    part[t] += v;
    __syncthreads();
  }
  int run = (t==0) ? 0 : part[t-1];
  for (int i=s0;i<s1;i++){ off[i]=run; run += c[i]; }
  if (t==0) off[n] = part[1023];
}

__global__ void k_copy_int(const int* __restrict__ a, int* __restrict__ b, int n){
  int i = blockIdx.x*blockDim.x+threadIdx.x;
  if (i<n) b[i]=a[i];
}

__global__ void k_fill(const int* __restrict__ dst, int m, int* __restrict__ cur, int* __restrict__ eid){
  int i = blockIdx.x*blockDim.x+threadIdx.x;
  if (i<m){ int p = atomicAdd(&cur[dst[i]],1); eid[p]=i; }
}

// ---------------- geometry ----------------
__global__ void k_geom_edge(const float* __restrict__ pos, const int* __restrict__ ei, float* __restrict__ d){
  int m = blockIdx.x*blockDim.x+threadIdx.x;
  if (m >= EE) return;
  int i0 = ei[m], i1 = ei[EE+m];
  float dx = pos[i0*3+0]-pos[i1*3+0]+1e-8f;
  float dy = pos[i0*3+1]-pos[i1*3+1]+1e-8f;
  float dz = pos[i0*3+2]-pos[i1*3+2]+1e-8f;
  d[m] = sqrtf(dx*dx+dy*dy+dz*dz);
}

__global__ void k_geom_tri(const float* __restrict__ pos, const int* __restrict__ ti, float* __restrict__ cosa){
  int m = blockIdx.x*blockDim.x+threadIdx.x;
  if (m >= TT) return;
  int i = ti[m], j = ti[TT+m], k = ti[2*TT+m];
  float ux = pos[i*3+0]-pos[j*3+0], uy = pos[i*3+1]-pos[j*3+1], uz = pos[i*3+2]-pos[j*3+2];
  float vx = pos[k*3+0]-pos[j*3+0], vy = pos[k*3+1]-pos[j*3+1], vz = pos[k*3+2]-pos[j*3+2];
  float num = ux*vx+uy*vy+uz*vz;
  float den = sqrtf(ux*ux+uy*uy+uz*uz)*sqrtf(vx*vx+vy*vy+vz*vz) + 1e-8f;
  cosa[m] = num/den;
}

__global__ void k_geom_quad(const float* __restrict__ pos, const int* __restrict__ qi, float* __restrict__ cosd){
  int m = blockIdx.x*blockDim.x+threadIdx.x;
  if (m >= QQ) return;
  int p0 = qi[m], p1 = qi[QQ+m], p2 = qi[2*QQ+m], p3 = qi[3*QQ+m];
  float b1x = pos[p1*3+0]-pos[p0*3+0], b1y = pos[p1*3+1]-pos[p0*3+1], b1z = pos[p1*3+2]-pos[p0*3+2];
  float b2x = pos[p2*3+0]-pos[p1*3+0], b2y = pos[p2*3+1]-pos[p1*3+1], b2z = pos[p2*3+2]-pos[p1*3+2];
  float b3x = pos[p3*3+0]-pos[p2*3+0], b3y = pos[p3*3+1]-pos[p2*3+1], b3z = pos[p3*3+2]-pos[p2*3+2];
  float n1x = b1y*b2z - b1z*b2y, n1y = b1z*b2x - b1x*b2z, n1z = b1x*b2y - b1y*b2x;
  float n2x = b2y*b3z - b2z*b3y, n2y = b2z*b3x - b2x*b3z, n2z = b2x*b3y - b2y*b3x;
  float num = n1x*n2x+n1y*n2y+n1z*n2z;
  float den = sqrtf(n1x*n1x+n1y*n1y+n1z*n1z)*sqrtf(n2x*n2x+n2y*n2y+n2z*n2z) + 1e-8f;
  cosd[m] = num/den;
}

// ---------------- GEMM hl = A @ W  (A: [n,128], W: [128,128]); also writes fp16 mirror ----------------
#define GR 16
__global__ __launch_bounds__(128) void k_gemm(const float* __restrict__ A, const float* __restrict__ W,
                                              float* __restrict__ B, __half* __restrict__ B16, int nrows){
  __shared__ float At[GR][HID];
  int col = threadIdx.x;
  for (int r0 = blockIdx.x*GR; r0 < nrows; r0 += gridDim.x*GR){
    int rmax = min(GR, nrows - r0);
    for (int i = threadIdx.x; i < rmax*HID; i += 128) At[i>>7][i&127] = A[(size_t)r0*HID + i];
    __syncthreads();
    float acc[GR];
    #pragma unroll
    for (int r=0;r<GR;r++) acc[r]=0.f;
    for (int k=0;k<HID;k++){
      float w = W[k*HID+col];
      #pragma unroll
      for (int r=0;r<GR;r++) acc[r] = fmaf(At[r][k], w, acc[r]);
    }
    for (int r=0;r<rmax;r++){
      size_t oi = (size_t)(r0+r)*HID+col;
      B[oi] = acc[r];
      B16[oi] = __float2half(acc[r]);
    }
    __syncthreads();
  }
}

// ---------------- per-node attention projections for the 3 hop types ----------------
__global__ void k_proj(const float* __restrict__ hl,
                       const float* __restrict__ ae, const float* __restrict__ at, const float* __restrict__ aq,
                       float* __restrict__ qa_e, float* __restrict__ ka_e,
                       float* __restrict__ qa_t, float* __restrict__ ka_t,
                       float* __restrict__ qa_q, float* __restrict__ ka_q){
  int i = blockIdx.x*blockDim.x + threadIdx.x;  // n*8+h
  if (i >= NN*NH) return;
  int h = i & 7; int n = i >> 3;
  const float* v = hl + (size_t)n*HID + h*DH;
  float x[DH];
  #pragma unroll
  for (int d=0; d<DH; d++) x[d] = v[d];
  const float* Ae = ae + h*33; const float* At_ = at + h*33; const float* Aq = aq + h*33;
  float s0=0,s1=0,s2=0,s3=0,s4=0,s5=0;
  #pragma unroll
  for (int d=0; d<DH; d++){
    s0 = fmaf(x[d], Ae[d],      s0);  s1 = fmaf(x[d], Ae[DH+d],  s1);
    s2 = fmaf(x[d], At_[d],     s2);  s3 = fmaf(x[d], At_[DH+d], s3);
    s4 = fmaf(x[d], Aq[d],      s4);  s5 = fmaf(x[d], Aq[DH+d],  s5);
  }
  qa_e[i]=s0; ka_e[i]=s1; qa_t[i]=s2; ka_t[i]=s3; qa_q[i]=s4; ka_q[i]=s5;
}

// ---------------- edge bias: edge_attr @ We[l]  ([E,16]x[16,8]) ----------------
__global__ void k_bias(const float* __restrict__ ea, const float* __restrict__ Wel, float* __restrict__ bias){
  int m = blockIdx.x*blockDim.x+threadIdx.x;
  if (m >= EE) return;
  float a[16];
  #pragma unroll
  for (int c=0;c<16;c++) a[c] = ea[(size_t)m*16+c];
  #pragma unroll
  for (int h=0;h<NH;h++){
    float s = 0.f;
    #pragma unroll
    for (int c=0;c<16;c++) s = fmaf(a[c], Wel[c*NH+h], s);
    bias[(size_t)m*NH+h] = s;
  }
}

// ---------------- fused hop: softmax over incoming edges + aggregation ----------------
// one block (128 threads) per destination node; thread t owns output dim t (head = t>>4)
// mode 0: agg = acc       mode 1: agg += acc      mode 2: hout = elu(hl + agg + acc)
__global__ __launch_bounds__(128) void k_hop(
    const int* __restrict__ off, const int* __restrict__ eid, const int* __restrict__ srcarr,
    const float* __restrict__ qa, const float* __restrict__ ka,
    const float* __restrict__ geom, const float* __restrict__ bias,
    const float* __restrict__ al,  // a[l] base [8][33]; coef = al[h*33+32]
    const __half* __restrict__ hh16,
    const float* __restrict__ hlr, float* __restrict__ agg, float* __restrict__ hout,
    int mode){
  __shared__ float sh_e[CHUNK*NH];
  __shared__ float sh_geom[CHUNK];
  __shared__ int   sh_src[CHUNK];
  __shared__ int   sh_eid[CHUNK];
  __shared__ float sh_s[NH];
  __shared__ float sh_coef[NH];
  __shared__ float sh_qa[NH];
  int n = blockIdx.x;
  int t = threadIdx.x;
  int start = off[n];
  int deg = off[n+1] - start;
  if (t < NH){ sh_s[t]=0.f; sh_coef[t]=al[t*33+32]; sh_qa[t]=qa[n*NH+t]; }
  __syncthreads();
  int ht = t >> 4;
  float acc = 0.f;
  if (deg > 0){
    bool onechunk = (deg <= CHUNK);
    // pass A: logits -> exp, denominators
    for (int base=0; base<deg; base+=CHUNK){
      int cd = min(CHUNK, deg-base);
      if (t < cd){
        int me = eid[start+base+t];
        sh_eid[t]=me; sh_src[t]=srcarr[me]; sh_geom[t]=geom[me];
      }
      __syncthreads();
      for (int i=t; i<cd*NH; i+=128){
        int m = i>>3, h = i&7;
        float lg = sh_qa[h] + ka[sh_src[m]*NH+h] + sh_geom[m]*sh_coef[h];
        if (bias) lg += bias[(size_t)sh_eid[m]*NH + h];
        lg = lg>=0.f ? lg : 0.2f*lg;
        float e = __expf(lg);
        if (onechunk) sh_e[i] = e;
        atomicAdd(&sh_s[h], e);
      }
      __syncthreads();
    }
    float sinv = 1.f/(sh_s[ht] + 1e-16f);
    // pass B: weighted aggregation of fp16 value rows
    if (onechunk){
      for (int m=0;m<deg;m++){
        float alpha = sh_e[m*NH+ht]*sinv;
        acc = fmaf(__half2float(hh16[(size_t)sh_src[m]*HID + t]), alpha, acc);
      }
    } else {
      for (int base=0; base<deg; base+=CHUNK){
        int cd = min(CHUNK, deg-base);
        __syncthreads();
        if (t < cd){
          int me = eid[start+base+t];
          sh_eid[t]=me; sh_src[t]=srcarr[me]; sh_geom[t]=geom[me];
        }
        __syncthreads();
        for (int i=t;i<cd*NH;i+=128){
          int m=i>>3, h=i&7;
          float lg = sh_qa[h] + ka[sh_src[m]*NH+h] + sh_geom[m]*sh_coef[h];
          if (bias) lg += bias[(size_t)sh_eid[m]*NH+h];
          lg = lg>=0.f ? lg : 0.2f*lg;
          sh_e[i] = __expf(lg);
        }
        __syncthreads();
        for (int m=0;m<cd;m++){
          float alpha = sh_e[m*NH+ht]*sinv;
          acc = fmaf(__half2float(hh16[(size_t)sh_src[m]*HID + t]), alpha, acc);
        }
      }
    }
  }
  size_t oi = (size_t)n*HID + t;
  if (mode == 0)      agg[oi] = acc;
  else if (mode == 1) agg[oi] += acc;
  else                hout[oi] = eluf(hlr[oi] + agg[oi] + acc);
}

// ---------------- graph offsets (batch is sorted) ----------------
__global__ void k_graph_offsets(const int* __restrict__ batch, int* __restrict__ goff){
  int g = blockIdx.x*blockDim.x+threadIdx.x;
  if (g > GG) return;
  int lo = 0, hi = NN;
  while (lo < hi){ int mid = (lo+hi)>>1; if (batch[mid] < g) lo = mid+1; else hi = mid; }
  goff[g] = lo;
}

// ---------------- pooling: sum + max per graph ----------------
__global__ __launch_bounds__(128) void k_pool(const float* __restrict__ h, const int* __restrict__ goff,
                                              float* __restrict__ gs, float* __restrict__ gmx){
  int g = blockIdx.x, t = threadIdx.x;
  int s = goff[g], e = goff[g+1];
  float sum = 0.f, mx = -INFINITY;
  for (int n=s; n<e; n++){
    float v = h[(size_t)n*HID+t];
    sum += v; mx = fmaxf(mx, v);
  }
  gs[(size_t)g*HID+t] = sum;
  gmx[(size_t)g*HID+t] = (s < e) ? mx : 0.f;
}

// ---------------- readout MLP: [257]->256->256->1, one block per graph ----------------
__global__ __launch_bounds__(256) void k_mlp(const float* __restrict__ gs, const float* __restrict__ gmx,
    const float* __restrict__ temps,
    const float* __restrict__ W1, const float* __restrict__ b1,
    const float* __restrict__ W2, const float* __restrict__ b2,
    const float* __restrict__ W3, const float* __restrict__ b3,
    float* __restrict__ out){
  __shared__ float mol[257];
  __shared__ float hd[256];
  __shared__ float red[256];
  int g = blockIdx.x, t = threadIdx.x;
  if (t < 128){ mol[t] = gs[(size_t)g*HID+t]; mol[128+t] = gmx[(size_t)g*HID+t]; }
  if (t == 0) mol[256] = temps[g];
  __syncthreads();
  float acc = b1[t];
  for (int k=0;k<257;k++) acc = fmaf(mol[k], W1[k*256+t], acc);
  hd[t] = eluf(acc);
  __syncthreads();
  acc = b2[t];
  for (int k=0;k<256;k++) acc = fmaf(hd[k], W2[k*256+t], acc);
  red[t] = eluf(acc) * W3[t];
  __syncthreads();
  for (int s=128;s>0;s>>=1){ if (t < s) red[t] += red[t+s]; __syncthreads(); }
  if (t == 0) out[g] = red[0] + b3[0];
}

extern "C" void kernel_launch(void* const* d_in, const int* in_sizes, int n_in,
                              void* d_out, int out_size, void* d_ws, size_t ws_size,
                              hipStream_t stream){
  const float* x         = (const float*)d_in[0];
  const float* pos       = (const float*)d_in[1];
  const float* edge_attr = (const float*)d_in[2];
  const float* temps     = (const float*)d_in[3];
  const int*   ei        = (const int*)d_in[4];
  const int*   ti        = (const int*)d_in[5];
  const int*   qi        = (const int*)d_in[6];
  const int*   batch     = (const int*)d_in[7];
  const float* W         = (const float*)d_in[8];
  const float* a_e       = (const float*)d_in[9];
  const float* a_t       = (const float*)d_in[10];
  const float* a_q       = (const float*)d_in[11];
  const float* We        = (const float*)d_in[12];
  const float* W1        = (const float*)d_in[13];
  const float* b1        = (const float*)d_in[14];
  const float* W2        = (const float*)d_in[15];
  const float* b2        = (const float*)d_in[16];
  const float* W3        = (const float*)d_in[17];
  const float* b3        = (const float*)d_in[18];
  float* out = (float*)d_out;

  char* base = (char*)d_ws; size_t woff = 0;
  auto alloc = [&](size_t bytes)->void*{
    void* p = base + woff;
    woff = (woff + bytes + 255) & ~(size_t)255;
    return p;
  };
  float*  hbuf  = (float*)alloc((size_t)NN*HID*4);
  float*  hl    = (float*)alloc((size_t)NN*HID*4);
  __half* hl16  = (__half*)alloc((size_t)NN*HID*2);
  float*  agg   = (float*)alloc((size_t)NN*HID*4);
  float*  qa_e  = (float*)alloc((size_t)NN*NH*4);
  float*  ka_e  = (float*)alloc((size_t)NN*NH*4);
  float*  qa_t  = (float*)alloc((size_t)NN*NH*4);
  float*  ka_t  = (float*)alloc((size_t)NN*NH*4);
  float*  qa_q  = (float*)alloc((size_t)NN*NH*4);
  float*  ka_q  = (float*)alloc((size_t)NN*NH*4);
  float*  dgeom = (float*)alloc((size_t)EE*4);
  float*  cosa  = (float*)alloc((size_t)TT*4);
  float*  cosd  = (float*)alloc((size_t)QQ*4);
  float*  biasE = (float*)alloc((size_t)EE*NH*4);
  float*  gs    = (float*)alloc((size_t)GG*HID*4);
  float*  gmx   = (float*)alloc((size_t)GG*HID*4);
  int* cnt     = (int*)alloc((size_t)3*NN*4);
  int* off_e   = (int*)alloc((size_t)(NN+1)*4);
  int* off_t   = (int*)alloc((size_t)(NN+1)*4);
  int* off_q   = (int*)alloc((size_t)(NN+1)*4);
  int* cur_e   = (int*)alloc((size_t)NN*4);
  int* cur_t   = (int*)alloc((size_t)NN*4);
  int* cur_q   = (int*)alloc((size_t)NN*4);
  int* eid_e   = (int*)alloc((size_t)EE*4);
  int* eid_t   = (int*)alloc((size_t)TT*4);
  int* eid_q   = (int*)alloc((size_t)QQ*4);
  int* goff    = (int*)alloc((size_t)(GG+1)*4);

  // ---- CSR build (dst rows: ei[0:E], ti[0:T], qi[0:Q]) ----
  hipMemsetAsync(cnt, 0, (size_t)3*NN*4, stream);
  k_count<<<(EE+255)/256,256,0,stream>>>(ei, EE, cnt);
  k_count<<<(TT+255)/256,256,0,stream>>>(ti, TT, cnt+NN);
  k_count<<<(QQ+255)/256,256,0,stream>>>(qi, QQ, cnt+2*NN);
  k_scan3<<<3,1024,0,stream>>>(cnt, off_e, off_t, off_q, NN);
  k_copy_int<<<(NN+255)/256,256,0,stream>>>(off_e, cur_e, NN);
  k_copy_int<<<(NN+255)/256,256,0,stream>>>(off_t, cur_t, NN);
  k_copy_int<<<(NN+255)/256,256,0,stream>>>(off_q, cur_q, NN);
  k_fill<<<(EE+255)/256,256,0,stream>>>(ei, EE, cur_e, eid_e);
  k_fill<<<(TT+255)/256,256,0,stream>>>(ti, TT, cur_t, eid_t);
  k_fill<<<(QQ+255)/256,256,0,stream>>>(qi, QQ, cur_q, eid_q);

  // ---- geometry ----
  k_geom_edge<<<(EE+255)/256,256,0,stream>>>(pos, ei, dgeom);
  k_geom_tri <<<(TT+255)/256,256,0,stream>>>(pos, ti, cosa);
  k_geom_quad<<<(QQ+255)/256,256,0,stream>>>(pos, qi, cosd);
  k_graph_offsets<<<(GG+1+255)/256,256,0,stream>>>(batch, goff);

  // ---- layers ----
  for (int l=0; l<3; l++){
    const float* hin = (l==0) ? x : hbuf;
    k_gemm<<<3125,128,0,stream>>>(hin, W + (size_t)l*HID*HID, hl, hl16, NN);
    k_proj<<<(NN*NH+255)/256,256,0,stream>>>(hl, a_e+l*264, a_t+l*264, a_q+l*264,
                                             qa_e, ka_e, qa_t, ka_t, qa_q, ka_q);
    k_bias<<<(EE+255)/256,256,0,stream>>>(edge_attr, We + l*DH*NH, biasE);
    k_hop<<<NN,128,0,stream>>>(off_e, eid_e, ei+EE,   qa_e, ka_e, dgeom, biasE,   a_e+l*264, hl16, hl, agg, nullptr, 0);
    k_hop<<<NN,128,0,stream>>>(off_t, eid_t, ti+2*TT, qa_t, ka_t, cosa,  nullptr, a_t+l*264, hl16, hl, agg, nullptr, 1);
    k_hop<<<NN,128,0,stream>>>(off_q, eid_q, qi+3*QQ, qa_q, ka_q, cosd,  nullptr, a_q+l*264, hl16, hl, agg, hbuf,    2);
  }

  // ---- readout ----
  k_pool<<<GG,128,0,stream>>>(hbuf, goff, gs, gmx);
  k_mlp<<<GG,256,0,stream>>>(gs, gmx, temps, W1, b1, W2, b2, W3, b3, out);
}

// Round 3
// 1439.493 us; speedup vs baseline: 1.4143x; 1.1365x over previous
//
#include <hip/hip_runtime.h>
#include <hip/hip_fp16.h>

#define NN 50000
#define EE 800000
#define TT 1000000
#define QQ 1000000
#define GG 4096
#define HID 128
#define NH 8
#define DH 16
#define CHUNK 128

__device__ __forceinline__ float eluf(float x){ return x > 0.f ? x : expm1f(x); }

// ---------------- count incident interactions per dst node (all 3 types, 1 launch) ----------------
__global__ void k_count3(const int* __restrict__ ei, const int* __restrict__ ti, const int* __restrict__ qi,
                         int* __restrict__ cnt){
  int i = blockIdx.x*blockDim.x + threadIdx.x;
  if (i < EE) atomicAdd(&cnt[ei[i]], 1);
  else if (i < EE+TT) atomicAdd(&cnt[NN + ti[i-EE]], 1);
  else if (i < EE+TT+QQ) atomicAdd(&cnt[2*NN + qi[i-EE-TT]], 1);
}

// ---------------- 3 scans (off+cur) + graph offsets, one launch (grid=4) ----------------
__global__ __launch_bounds__(1024) void k_scan4(const int* __restrict__ cnt,
    int* __restrict__ off_e, int* __restrict__ off_t, int* __restrict__ off_q,
    int* __restrict__ cur_e, int* __restrict__ cur_t, int* __restrict__ cur_q,
    const int* __restrict__ batch, int* __restrict__ goff){
  int b = blockIdx.x, t = threadIdx.x;
  if (b == 3){
    for (int g=t; g<=GG; g+=1024){
      int lo=0, hi=NN;
      while (lo<hi){ int mid=(lo+hi)>>1; if (batch[mid]<g) lo=mid+1; else hi=mid; }
      goff[g]=lo;
    }
    return;
  }
  __shared__ int part[1024];
  const int* c = cnt + b*NN;
  int* off = (b==0)?off_e:(b==1)?off_t:off_q;
  int* cur = (b==0)?cur_e:(b==1)?cur_t:cur_q;
  int chunk = (NN + 1023) >> 10;
  int s0 = t*chunk, s1 = min(NN, s0+chunk);
  int sum = 0;
  for (int i=s0;i<s1;i++) sum += c[i];
  part[t] = sum;
  __syncthreads();
  for (int d=1; d<1024; d<<=1){
    int v = (t>=d) ? part[t-d] : 0;
    __syncthreads();
    part[t] += v;
    __syncthreads();
  }
  int run = (t==0) ? 0 : part[t-1];
  for (int i=s0;i<s1;i++){ off[i]=run; cur[i]=run; run += c[i]; }
  if (t==0) off[NN] = part[1023];
}

// ---------------- fill CSR (src + geometry permuted to CSR order; epos for edge bias) ----------------
__global__ void k_fillgeom(const float* __restrict__ pos,
    const int* __restrict__ ei, const int* __restrict__ ti, const int* __restrict__ qi,
    int* __restrict__ cur_e, int* __restrict__ cur_t, int* __restrict__ cur_q,
    int* __restrict__ csrc_e, int* __restrict__ csrc_t, int* __restrict__ csrc_q,
    float* __restrict__ cg_e, float* __restrict__ cg_t, float* __restrict__ cg_q,
    int* __restrict__ epos_e){
  int i = blockIdx.x*blockDim.x + threadIdx.x;
  if (i < EE){
    int dn = ei[i], sn = ei[EE+i];
    float dx = pos[dn*3+0]-pos[sn*3+0]+1e-8f;
    float dy = pos[dn*3+1]-pos[sn*3+1]+1e-8f;
    float dz = pos[dn*3+2]-pos[sn*3+2]+1e-8f;
    float d = sqrtf(dx*dx+dy*dy+dz*dz);
    int p = atomicAdd(&cur_e[dn], 1);
    csrc_e[p] = sn; cg_e[p] = d; epos_e[i] = p;
  } else if (i < EE+TT){
    int m = i-EE;
    int a = ti[m], b = ti[TT+m], c = ti[2*TT+m];
    float ux = pos[a*3+0]-pos[b*3+0], uy = pos[a*3+1]-pos[b*3+1], uz = pos[a*3+2]-pos[b*3+2];
    float vx = pos[c*3+0]-pos[b*3+0], vy = pos[c*3+1]-pos[b*3+1], vz = pos[c*3+2]-pos[b*3+2];
    float num = ux*vx+uy*vy+uz*vz;
    float den = sqrtf(ux*ux+uy*uy+uz*uz)*sqrtf(vx*vx+vy*vy+vz*vz) + 1e-8f;
    int p = atomicAdd(&cur_t[a], 1);
    csrc_t[p] = c; cg_t[p] = num/den;
  } else if (i < EE+TT+QQ){
    int m = i-EE-TT;
    int p0 = qi[m], p1 = qi[QQ+m], p2 = qi[2*QQ+m], p3 = qi[3*QQ+m];
    float b1x = pos[p1*3+0]-pos[p0*3+0], b1y = pos[p1*3+1]-pos[p0*3+1], b1z = pos[p1*3+2]-pos[p0*3+2];
    float b2x = pos[p2*3+0]-pos[p1*3+0], b2y = pos[p2*3+1]-pos[p1*3+1], b2z = pos[p2*3+2]-pos[p1*3+2];
    float b3x = pos[p3*3+0]-pos[p2*3+0], b3y = pos[p3*3+1]-pos[p2*3+1], b3z = pos[p3*3+2]-pos[p2*3+2];
    float n1x = b1y*b2z - b1z*b2y, n1y = b1z*b2x - b1x*b2z, n1z = b1x*b2y - b1y*b2x;
    float n2x = b2y*b3z - b2z*b3y, n2y = b2z*b3x - b2x*b3z, n2z = b2x*b3y - b2y*b3x;
    float num = n1x*n2x+n1y*n2y+n1z*n2z;
    float den = sqrtf(n1x*n1x+n1y*n1y+n1z*n1z)*sqrtf(n2x*n2x+n2y*n2y+n2z*n2z) + 1e-8f;
    int p = atomicAdd(&cur_q[p0], 1);
    csrc_q[p] = p3; cg_q[p] = num/den;
  }
}

// ---------------- GEMM hl = A @ W  (A: [n,128], W: [128,128]); also writes fp16 mirror ----------------
#define GR 16
__global__ __launch_bounds__(128) void k_gemm(const float* __restrict__ A, const float* __restrict__ W,
                                              float* __restrict__ B, __half* __restrict__ B16, int nrows){
  __shared__ float At[GR][HID];
  int col = threadIdx.x;
  for (int r0 = blockIdx.x*GR; r0 < nrows; r0 += gridDim.x*GR){
    int rmax = min(GR, nrows - r0);
    for (int i = threadIdx.x; i < rmax*HID; i += 128) At[i>>7][i&127] = A[(size_t)r0*HID + i];
    __syncthreads();
    float acc[GR];
    #pragma unroll
    for (int r=0;r<GR;r++) acc[r]=0.f;
    for (int k=0;k<HID;k++){
      float w = W[k*HID+col];
      #pragma unroll
      for (int r=0;r<GR;r++) acc[r] = fmaf(At[r][k], w, acc[r]);
    }
    for (int r=0;r<rmax;r++){
      size_t oi = (size_t)(r0+r)*HID+col;
      B[oi] = acc[r];
      B16[oi] = __float2half(acc[r]);
    }
    __syncthreads();
  }
}

// ---------------- per-node attn projections (NN*8 threads) + edge bias permuted to CSR (EE threads) ----------------
__global__ void k_projbias(const float* __restrict__ hl,
    const float* __restrict__ ae, const float* __restrict__ at, const float* __restrict__ aq,
    const float* __restrict__ ea, const float* __restrict__ Wel, const int* __restrict__ epos_e,
    float* __restrict__ qa_e, float* __restrict__ ka_e,
    float* __restrict__ qa_t, float* __restrict__ ka_t,
    float* __restrict__ qa_q, float* __restrict__ ka_q,
    float* __restrict__ biasP){
  int i = blockIdx.x*blockDim.x + threadIdx.x;
  if (i < NN*NH){
    int h = i & 7; int n = i >> 3;
    const float* v = hl + (size_t)n*HID + h*DH;
    float x[DH];
    #pragma unroll
    for (int d=0; d<DH; d++) x[d] = v[d];
    const float* Ae = ae + h*33; const float* At_ = at + h*33; const float* Aq = aq + h*33;
    float s0=0,s1=0,s2=0,s3=0,s4=0,s5=0;
    #pragma unroll
    for (int d=0; d<DH; d++){
      s0 = fmaf(x[d], Ae[d],      s0);  s1 = fmaf(x[d], Ae[DH+d],  s1);
      s2 = fmaf(x[d], At_[d],     s2);  s3 = fmaf(x[d], At_[DH+d], s3);
      s4 = fmaf(x[d], Aq[d],      s4);  s5 = fmaf(x[d], Aq[DH+d],  s5);
    }
    qa_e[i]=s0; ka_e[i]=s1; qa_t[i]=s2; ka_t[i]=s3; qa_q[i]=s4; ka_q[i]=s5;
  } else {
    int m = i - NN*NH;
    if (m < EE){
      float a[16];
      #pragma unroll
      for (int c=0;c<16;c++) a[c] = ea[(size_t)m*16+c];
      size_t p = (size_t)epos_e[m]*NH;
      #pragma unroll
      for (int h=0;h<NH;h++){
        float s = 0.f;
        #pragma unroll
        for (int c=0;c<16;c++) s = fmaf(a[c], Wel[c*NH+h], s);
        biasP[p+h] = s;
      }
    }
  }
}

// ---------------- fused 3-hop attention + residual + ELU, one block per node ----------------
// single pass per hop: agg = (sum e*v) / (sum e)  (softmax max-shift cancels; logits are O(+-4))
__global__ __launch_bounds__(128) void k_hop3(
    const int* __restrict__ off_e, const int* __restrict__ off_t, const int* __restrict__ off_q,
    const int* __restrict__ csrc_e, const int* __restrict__ csrc_t, const int* __restrict__ csrc_q,
    const float* __restrict__ cg_e, const float* __restrict__ cg_t, const float* __restrict__ cg_q,
    const float* __restrict__ biasP,
    const float* __restrict__ qa_e, const float* __restrict__ ka_e,
    const float* __restrict__ qa_t, const float* __restrict__ ka_t,
    const float* __restrict__ qa_q, const float* __restrict__ ka_q,
    const float* __restrict__ ae, const float* __restrict__ at, const float* __restrict__ aq,
    const __half* __restrict__ hh16, const float* __restrict__ hlr, float* __restrict__ hout){
  __shared__ float sh_e[CHUNK*NH];     // 4 KB
  __shared__ float sh_bias[CHUNK*NH];  // 4 KB (e-hop only)
  __shared__ int   sh_src[CHUNK];
  __shared__ float sh_geom[CHUNK];
  __shared__ float sh_s[3*NH];
  __shared__ float sh_qa[3*NH];
  __shared__ float sh_coef[3*NH];
  int n = blockIdx.x, t = threadIdx.x;
  if (t < 24){
    int p = t>>3, h = t&7;
    const float* a  = (p==0)?ae:(p==1)?at:aq;
    const float* qa = (p==0)?qa_e:(p==1)?qa_t:qa_q;
    sh_coef[t] = a[h*33+32];
    sh_qa[t]   = qa[n*NH+h];
    sh_s[t]    = 0.f;
  }
  __syncthreads();
  int ht = t >> 4;
  float acc = 0.f;
  #pragma unroll
  for (int p=0; p<3; p++){
    const int*   off  = (p==0)?off_e :(p==1)?off_t :off_q;
    const int*   csrc = (p==0)?csrc_e:(p==1)?csrc_t:csrc_q;
    const float* cg   = (p==0)?cg_e  :(p==1)?cg_t  :cg_q;
    const float* ka   = (p==0)?ka_e  :(p==1)?ka_t  :ka_q;
    int start = off[n];
    int deg = off[n+1] - start;
    float tmp = 0.f;
    for (int base=0; base<deg; base+=CHUNK){
      int cd = min(CHUNK, deg-base);
      if (t < cd){
        sh_src[t]  = csrc[start+base+t];
        sh_geom[t] = cg[start+base+t];
      }
      if (p == 0){
        for (int i=t; i<cd*NH; i+=128) sh_bias[i] = biasP[(size_t)(start+base)*NH + i];
      }
      __syncthreads();
      for (int i=t; i<cd*NH; i+=128){
        int m = i>>3, h = i&7;
        float lg = sh_qa[p*8+h] + ka[sh_src[m]*NH+h] + sh_geom[m]*sh_coef[p*8+h];
        if (p == 0) lg += sh_bias[i];
        lg = lg>=0.f ? lg : 0.2f*lg;
        float e = __expf(lg);
        sh_e[i] = e;
        atomicAdd(&sh_s[p*8+h], e);
      }
      __syncthreads();
      int m = 0;
      for (; m+4 <= cd; m += 4){
        float v0 = __half2float(hh16[(size_t)sh_src[m+0]*HID + t]);
        float v1 = __half2float(hh16[(size_t)sh_src[m+1]*HID + t]);
        float v2 = __half2float(hh16[(size_t)sh_src[m+2]*HID + t]);
        float v3 = __half2float(hh16[(size_t)sh_src[m+3]*HID + t]);
        tmp = fmaf(v0, sh_e[(m+0)*NH+ht], tmp);
        tmp = fmaf(v1, sh_e[(m+1)*NH+ht], tmp);
        tmp = fmaf(v2, sh_e[(m+2)*NH+ht], tmp);
        tmp = fmaf(v3, sh_e[(m+3)*NH+ht], tmp);
      }
      for (; m<cd; m++)
        tmp = fmaf(__half2float(hh16[(size_t)sh_src[m]*HID + t]), sh_e[m*NH+ht], tmp);
      __syncthreads();
    }
    acc += tmp / (sh_s[p*8+ht] + 1e-16f);
  }
  size_t oi = (size_t)n*HID + t;
  hout[oi] = eluf(hlr[oi] + acc);
}

// ---------------- pooling: sum + max per graph ----------------
__global__ __launch_bounds__(128) void k_pool(const float* __restrict__ h, const int* __restrict__ goff,
                                              float* __restrict__ gs, float* __restrict__ gmx){
  int g = blockIdx.x, t = threadIdx.x;
  int s = goff[g], e = goff[g+1];
  float sum = 0.f, mx = -INFINITY;
  for (int n=s; n<e; n++){
    float v = h[(size_t)n*HID+t];
    sum += v; mx = fmaxf(mx, v);
  }
  gs[(size_t)g*HID+t] = sum;
  gmx[(size_t)g*HID+t] = (s < e) ? mx : 0.f;
}

// ---------------- readout MLP: [257]->256->256->1, one block per graph ----------------
__global__ __launch_bounds__(256) void k_mlp(const float* __restrict__ gs, const float* __restrict__ gmx,
    const float* __restrict__ temps,
    const float* __restrict__ W1, const float* __restrict__ b1,
    const float* __restrict__ W2, const float* __restrict__ b2,
    const float* __restrict__ W3, const float* __restrict__ b3,
    float* __restrict__ out){
  __shared__ float mol[257];
  __shared__ float hd[256];
  __shared__ float red[256];
  int g = blockIdx.x, t = threadIdx.x;
  if (t < 128){ mol[t] = gs[(size_t)g*HID+t]; mol[128+t] = gmx[(size_t)g*HID+t]; }
  if (t == 0) mol[256] = temps[g];
  __syncthreads();
  float acc = b1[t];
  for (int k=0;k<257;k++) acc = fmaf(mol[k], W1[k*256+t], acc);
  hd[t] = eluf(acc);
  __syncthreads();
  acc = b2[t];
  for (int k=0;k<256;k++) acc = fmaf(hd[k], W2[k*256+t], acc);
  red[t] = eluf(acc) * W3[t];
  __syncthreads();
  for (int s=128;s>0;s>>=1){ if (t < s) red[t] += red[t+s]; __syncthreads(); }
  if (t == 0) out[g] = red[0] + b3[0];
}

extern "C" void kernel_launch(void* const* d_in, const int* in_sizes, int n_in,
                              void* d_out, int out_size, void* d_ws, size_t ws_size,
                              hipStream_t stream){
  const float* x         = (const float*)d_in[0];
  const float* pos       = (const float*)d_in[1];
  const float* edge_attr = (const float*)d_in[2];
  const float* temps     = (const float*)d_in[3];
  const int*   ei        = (const int*)d_in[4];
  const int*   ti        = (const int*)d_in[5];
  const int*   qi        = (const int*)d_in[6];
  const int*   batch     = (const int*)d_in[7];
  const float* W         = (const float*)d_in[8];
  const float* a_e       = (const float*)d_in[9];
  const float* a_t       = (const float*)d_in[10];
  const float* a_q       = (const float*)d_in[11];
  const float* We        = (const float*)d_in[12];
  const float* W1        = (const float*)d_in[13];
  const float* b1        = (const float*)d_in[14];
  const float* W2        = (const float*)d_in[15];
  const float* b2        = (const float*)d_in[16];
  const float* W3        = (const float*)d_in[17];
  const float* b3        = (const float*)d_in[18];
  float* out = (float*)d_out;

  char* base = (char*)d_ws; size_t woff = 0;
  auto alloc = [&](size_t bytes)->void*{
    void* p = base + woff;
    woff = (woff + bytes + 255) & ~(size_t)255;
    return p;
  };
  float*  hbuf   = (float*)alloc((size_t)NN*HID*4);
  float*  hl     = (float*)alloc((size_t)NN*HID*4);
  __half* hl16   = (__half*)alloc((size_t)NN*HID*2);
  float*  qa_e   = (float*)alloc((size_t)NN*NH*4);
  float*  ka_e   = (float*)alloc((size_t)NN*NH*4);
  float*  qa_t   = (float*)alloc((size_t)NN*NH*4);
  float*  ka_t   = (float*)alloc((size_t)NN*NH*4);
  float*  qa_q   = (float*)alloc((size_t)NN*NH*4);
  float*  ka_q   = (float*)alloc((size_t)NN*NH*4);
  int*    csrc_e = (int*)alloc((size_t)EE*4);
  int*    csrc_t = (int*)alloc((size_t)TT*4);
  int*    csrc_q = (int*)alloc((size_t)QQ*4);
  float*  cg_e   = (float*)alloc((size_t)EE*4);
  float*  cg_t   = (float*)alloc((size_t)TT*4);
  float*  cg_q   = (float*)alloc((size_t)QQ*4);
  float*  biasP  = (float*)alloc((size_t)EE*NH*4);
  int*    epos_e = (int*)alloc((size_t)EE*4);
  float*  gs     = (float*)alloc((size_t)GG*HID*4);
  float*  gmx    = (float*)alloc((size_t)GG*HID*4);
  int*    cnt    = (int*)alloc((size_t)3*NN*4);
  int*    off_e  = (int*)alloc((size_t)(NN+1)*4);
  int*    off_t  = (int*)alloc((size_t)(NN+1)*4);
  int*    off_q  = (int*)alloc((size_t)(NN+1)*4);
  int*    cur_e  = (int*)alloc((size_t)NN*4);
  int*    cur_t  = (int*)alloc((size_t)NN*4);
  int*    cur_q  = (int*)alloc((size_t)NN*4);
  int*    goff   = (int*)alloc((size_t)(GG+1)*4);

  // ---- CSR build + geometry (4 launches) ----
  hipMemsetAsync(cnt, 0, (size_t)3*NN*4, stream);
  int tot = EE+TT+QQ;
  k_count3<<<(tot+255)/256,256,0,stream>>>(ei, ti, qi, cnt);
  k_scan4<<<4,1024,0,stream>>>(cnt, off_e, off_t, off_q, cur_e, cur_t, cur_q, batch, goff);
  k_fillgeom<<<(tot+255)/256,256,0,stream>>>(pos, ei, ti, qi, cur_e, cur_t, cur_q,
                                             csrc_e, csrc_t, csrc_q, cg_e, cg_t, cg_q, epos_e);

  // ---- layers ----
  for (int l=0; l<3; l++){
    const float* hin = (l==0) ? x : hbuf;
    k_gemm<<<3125,128,0,stream>>>(hin, W + (size_t)l*HID*HID, hl, hl16, NN);
    k_projbias<<<(NN*NH+EE+255)/256,256,0,stream>>>(hl, a_e+l*264, a_t+l*264, a_q+l*264,
                                                    edge_attr, We + l*DH*NH, epos_e,
                                                    qa_e, ka_e, qa_t, ka_t, qa_q, ka_q, biasP);
    k_hop3<<<NN,128,0,stream>>>(off_e, off_t, off_q, csrc_e, csrc_t, csrc_q,
                                cg_e, cg_t, cg_q, biasP,
                                qa_e, ka_e, qa_t, ka_t, qa_q, ka_q,
                                a_e+l*264, a_t+l*264, a_q+l*264,
                                hl16, hl, hbuf);
  }

  // ---- readout ----
  k_pool<<<GG,128,0,stream>>>(hbuf, goff, gs, gmx);
  k_mlp<<<GG,256,0,stream>>>(gs, gmx, temps, W1, b1, W2, b2, W3, b3, out);
}

// Round 4
// 1253.306 us; speedup vs baseline: 1.6244x; 1.1486x over previous
//
#include <hip/hip_runtime.h>
#include <hip/hip_fp16.h>

#define NN 50000
#define EE 800000
#define TT 1000000
#define QQ 1000000
#define GG 4096
#define HID 128
#define NH 8
#define DH 16
#define CAPC 96

__device__ __forceinline__ float eluf(float x){ return x > 0.f ? x : expm1f(x); }

// ---------------- count incident interactions per dst node (all 3 types, 1 launch) ----------------
__global__ void k_count3(const int* __restrict__ ei, const int* __restrict__ ti, const int* __restrict__ qi,
                         int* __restrict__ cnt){
  int i = blockIdx.x*blockDim.x + threadIdx.x;
  if (i < EE) atomicAdd(&cnt[ei[i]], 1);
  else if (i < EE+TT) atomicAdd(&cnt[NN + ti[i-EE]], 1);
  else if (i < EE+TT+QQ) atomicAdd(&cnt[2*NN + qi[i-EE-TT]], 1);
}

// ---------------- 3 scans (off+cur) + graph offsets, one launch (grid=4) ----------------
__global__ __launch_bounds__(1024) void k_scan4(const int* __restrict__ cnt,
    int* __restrict__ off_e, int* __restrict__ off_t, int* __restrict__ off_q,
    int* __restrict__ cur_e, int* __restrict__ cur_t, int* __restrict__ cur_q,
    const int* __restrict__ batch, int* __restrict__ goff){
  int b = blockIdx.x, t = threadIdx.x;
  if (b == 3){
    for (int g=t; g<=GG; g+=1024){
      int lo=0, hi=NN;
      while (lo<hi){ int mid=(lo+hi)>>1; if (batch[mid]<g) lo=mid+1; else hi=mid; }
      goff[g]=lo;
    }
    return;
  }
  __shared__ int part[1024];
  const int* c = cnt + b*NN;
  int* off = (b==0)?off_e:(b==1)?off_t:off_q;
  int* cur = (b==0)?cur_e:(b==1)?cur_t:cur_q;
  int chunk = (NN + 1023) >> 10;
  int s0 = t*chunk, s1 = min(NN, s0+chunk);
  int sum = 0;
  for (int i=s0;i<s1;i++) sum += c[i];
  part[t] = sum;
  __syncthreads();
  for (int d=1; d<1024; d<<=1){
    int v = (t>=d) ? part[t-d] : 0;
    __syncthreads();
    part[t] += v;
    __syncthreads();
  }
  int run = (t==0) ? 0 : part[t-1];
  for (int i=s0;i<s1;i++){ off[i]=run; cur[i]=run; run += c[i]; }
  if (t==0) off[NN] = part[1023];
}

// ---------------- fill CSR (src + geometry permuted to CSR order; epos for edge bias) ----------------
__global__ void k_fillgeom(const float* __restrict__ pos,
    const int* __restrict__ ei, const int* __restrict__ ti, const int* __restrict__ qi,
    int* __restrict__ cur_e, int* __restrict__ cur_t, int* __restrict__ cur_q,
    int* __restrict__ csrc_e, int* __restrict__ csrc_t, int* __restrict__ csrc_q,
    float* __restrict__ cg_e, float* __restrict__ cg_t, float* __restrict__ cg_q,
    int* __restrict__ epos_e){
  int i = blockIdx.x*blockDim.x + threadIdx.x;
  if (i < EE){
    int dn = ei[i], sn = ei[EE+i];
    float dx = pos[dn*3+0]-pos[sn*3+0]+1e-8f;
    float dy = pos[dn*3+1]-pos[sn*3+1]+1e-8f;
    float dz = pos[dn*3+2]-pos[sn*3+2]+1e-8f;
    float d = sqrtf(dx*dx+dy*dy+dz*dz);
    int p = atomicAdd(&cur_e[dn], 1);
    csrc_e[p] = sn; cg_e[p] = d; epos_e[i] = p;
  } else if (i < EE+TT){
    int m = i-EE;
    int a = ti[m], b = ti[TT+m], c = ti[2*TT+m];
    float ux = pos[a*3+0]-pos[b*3+0], uy = pos[a*3+1]-pos[b*3+1], uz = pos[a*3+2]-pos[b*3+2];
    float vx = pos[c*3+0]-pos[b*3+0], vy = pos[c*3+1]-pos[b*3+1], vz = pos[c*3+2]-pos[b*3+2];
    float num = ux*vx+uy*vy+uz*vz;
    float den = sqrtf(ux*ux+uy*uy+uz*uz)*sqrtf(vx*vx+vy*vy+vz*vz) + 1e-8f;
    int p = atomicAdd(&cur_t[a], 1);
    csrc_t[p] = c; cg_t[p] = num/den;
  } else if (i < EE+TT+QQ){
    int m = i-EE-TT;
    int p0 = qi[m], p1 = qi[QQ+m], p2 = qi[2*QQ+m], p3 = qi[3*QQ+m];
    float b1x = pos[p1*3+0]-pos[p0*3+0], b1y = pos[p1*3+1]-pos[p0*3+1], b1z = pos[p1*3+2]-pos[p0*3+2];
    float b2x = pos[p2*3+0]-pos[p1*3+0], b2y = pos[p2*3+1]-pos[p1*3+1], b2z = pos[p2*3+2]-pos[p1*3+2];
    float b3x = pos[p3*3+0]-pos[p2*3+0], b3y = pos[p3*3+1]-pos[p2*3+1], b3z = pos[p3*3+2]-pos[p2*3+2];
    float n1x = b1y*b2z - b1z*b2y, n1y = b1z*b2x - b1x*b2z, n1z = b1x*b2y - b1y*b2x;
    float n2x = b2y*b3z - b2z*b3y, n2y = b2z*b3x - b2x*b3z, n2z = b2x*b3y - b2y*b3x;
    float num = n1x*n2x+n1y*n2y+n1z*n2z;
    float den = sqrtf(n1x*n1x+n1y*n1y+n1z*n1z)*sqrtf(n2x*n2x+n2y*n2y+n2z*n2z) + 1e-8f;
    int p = atomicAdd(&cur_q[p0], 1);
    csrc_q[p] = p3; cg_q[p] = num/den;
  }
}

// ---------------- GEMM hl = A @ W  (A: [n,128], W: [128,128]); no LDS: A rows are
// wave-uniform -> scalar loads; W reads coalesced (L2-resident). Also writes fp16 mirror.
#define GR 16
__global__ __launch_bounds__(128) void k_gemm(const float* __restrict__ A, const float* __restrict__ W,
                                              float* __restrict__ B, __half* __restrict__ B16){
  int col = threadIdx.x;
  int r0 = blockIdx.x * GR;
  const float* Ab = A + (size_t)r0*HID;
  float acc[GR];
  #pragma unroll
  for (int r=0;r<GR;r++) acc[r]=0.f;
  #pragma unroll 4
  for (int k=0;k<HID;k++){
    float wv = W[k*HID+col];
    #pragma unroll
    for (int r=0;r<GR;r++) acc[r] = fmaf(Ab[r*HID+k], wv, acc[r]);
  }
  #pragma unroll
  for (int r=0;r<GR;r++){
    size_t oi = (size_t)(r0+r)*HID+col;
    B[oi] = acc[r];
    B16[oi] = __float2half(acc[r]);
  }
}

// ---------------- per-node attn projections (NN*8 threads) + edge bias permuted to CSR (EE threads) ----------------
__global__ void k_projbias(const float* __restrict__ hl,
    const float* __restrict__ ae, const float* __restrict__ at, const float* __restrict__ aq,
    const float* __restrict__ ea, const float* __restrict__ Wel, const int* __restrict__ epos_e,
    float* __restrict__ qa_e, float* __restrict__ ka_e,
    float* __restrict__ qa_t, float* __restrict__ ka_t,
    float* __restrict__ qa_q, float* __restrict__ ka_q,
    float* __restrict__ biasP){
  int i = blockIdx.x*blockDim.x + threadIdx.x;
  if (i < NN*NH){
    int h = i & 7; int n = i >> 3;
    const float* v = hl + (size_t)n*HID + h*DH;
    float x[DH];
    #pragma unroll
    for (int d=0; d<DH; d++) x[d] = v[d];
    const float* Ae = ae + h*33; const float* At_ = at + h*33; const float* Aq = aq + h*33;
    float s0=0,s1=0,s2=0,s3=0,s4=0,s5=0;
    #pragma unroll
    for (int d=0; d<DH; d++){
      s0 = fmaf(x[d], Ae[d],      s0);  s1 = fmaf(x[d], Ae[DH+d],  s1);
      s2 = fmaf(x[d], At_[d],     s2);  s3 = fmaf(x[d], At_[DH+d], s3);
      s4 = fmaf(x[d], Aq[d],      s4);  s5 = fmaf(x[d], Aq[DH+d],  s5);
    }
    qa_e[i]=s0; ka_e[i]=s1; qa_t[i]=s2; ka_t[i]=s3; qa_q[i]=s4; ka_q[i]=s5;
  } else {
    int m = i - NN*NH;
    if (m < EE){
      float a[16];
      #pragma unroll
      for (int c=0;c<16;c++) a[c] = ea[(size_t)m*16+c];
      size_t p = (size_t)epos_e[m]*NH;
      #pragma unroll
      for (int h=0;h<NH;h++){
        float s = 0.f;
        #pragma unroll
        for (int c=0;c<16;c++) s = fmaf(a[c], Wel[c*NH+h], s);
        biasP[p+h] = s;
      }
    }
  }
}

// ---------------- fused 3-hop attention + residual + ELU, one block (128 thr) per node ----
// single-pass softmax (max-shift cancels; logits are O(+-4)); denominators via shfl reduce;
// value gather: half2 loads, wave-parity row split.
__global__ __launch_bounds__(128) void k_hop3(
    const int* __restrict__ off_e, const int* __restrict__ off_t, const int* __restrict__ off_q,
    const int* __restrict__ csrc_e, const int* __restrict__ csrc_t, const int* __restrict__ csrc_q,
    const float* __restrict__ cg_e, const float* __restrict__ cg_t, const float* __restrict__ cg_q,
    const float* __restrict__ biasP,
    const float* __restrict__ qa_e, const float* __restrict__ ka_e,
    const float* __restrict__ qa_t, const float* __restrict__ ka_t,
    const float* __restrict__ qa_q, const float* __restrict__ ka_q,
    const float* __restrict__ ae, const float* __restrict__ at, const float* __restrict__ aq,
    const __half* __restrict__ hh16, const float* __restrict__ hlr, float* __restrict__ hout){
  __shared__ float sh_e[3][CAPC*NH];   // 9216 B (reused as reduction buffer at tail)
  __shared__ int   sh_src[3][CAPC];    // 1152 B
  __shared__ float sh_s[3*NH];
  __shared__ float sh_qa[3*NH];
  __shared__ float sh_coef[3*NH];
  int n = blockIdx.x, t = threadIdx.x;
  int w = t >> 6, l = t & 63;
  if (t < 24){
    int p = t>>3, h = t&7;
    const float* a  = (p==0)?ae:(p==1)?at:aq;
    const float* qa = (p==0)?qa_e:(p==1)?qa_t:qa_q;
    sh_coef[t] = a[h*33+32];
    sh_qa[t]   = qa[n*NH+h];
    sh_s[t]    = 0.f;
  }
  int st_e = off_e[n], de = off_e[n+1]-st_e;
  int st_t = off_t[n], dt = off_t[n+1]-st_t;
  int st_q = off_q[n], dq = off_q[n+1]-st_q;
  __syncthreads();
  float aE0=0,aE1=0,aT0=0,aT1=0,aQ0=0,aQ1=0;
  int h  = t & 7;        // head for logit items
  int hg = l >> 3;       // head for gathered dims (2l, 2l+1)
  int maxd = max(de, max(dt, dq));
  for (int base=0; base<maxd; base+=CAPC){
    int ce = min(CAPC, de-base); if (ce<0) ce=0;
    int ct = min(CAPC, dt-base); if (ct<0) ct=0;
    int cq = min(CAPC, dq-base); if (cq<0) cq=0;
    if (t < ce) sh_src[0][t] = csrc_e[st_e+base+t];
    if (t < ct) sh_src[1][t] = csrc_t[st_t+base+t];
    if (t < cq) sh_src[2][t] = csrc_q[st_q+base+t];
    __syncthreads();
    // ---- logits for all 3 hops; private denominators (h fixed per thread) ----
    float dE=0.f, dT=0.f, dQ=0.f;
    for (int i=t; i<ce*NH; i+=128){
      int m = i>>3;
      float lg = sh_qa[h] + ka_e[sh_src[0][m]*NH+h] + cg_e[st_e+base+m]*sh_coef[h]
               + biasP[(size_t)(st_e+base)*NH + i];
      lg = lg>=0.f ? lg : 0.2f*lg;
      float e = __expf(lg);
      sh_e[0][i] = e; dE += e;
    }
    for (int i=t; i<ct*NH; i+=128){
      int m = i>>3;
      float lg = sh_qa[8+h] + ka_t[sh_src[1][m]*NH+h] + cg_t[st_t+base+m]*sh_coef[8+h];
      lg = lg>=0.f ? lg : 0.2f*lg;
      float e = __expf(lg);
      sh_e[1][i] = e; dT += e;
    }
    for (int i=t; i<cq*NH; i+=128){
      int m = i>>3;
      float lg = sh_qa[16+h] + ka_q[sh_src[2][m]*NH+h] + cg_q[st_q+base+m]*sh_coef[16+h];
      lg = lg>=0.f ? lg : 0.2f*lg;
      float e = __expf(lg);
      sh_e[2][i] = e; dQ += e;
    }
    // reduce the 8 same-head lanes of each wave, then 16 LDS adds per hop
    dE += __shfl_xor(dE, 8); dE += __shfl_xor(dE, 16); dE += __shfl_xor(dE, 32);
    dT += __shfl_xor(dT, 8); dT += __shfl_xor(dT, 16); dT += __shfl_xor(dT, 32);
    dQ += __shfl_xor(dQ, 8); dQ += __shfl_xor(dQ, 16); dQ += __shfl_xor(dQ, 32);
    if (l < 8){
      atomicAdd(&sh_s[l], dE);
      atomicAdd(&sh_s[8+l], dT);
      atomicAdd(&sh_s[16+l], dQ);
    }
    __syncthreads();
    // ---- gather: wave w handles rows m == w (mod 2); half2 loads (dims 2l, 2l+1) ----
    {
      int m = w;
      for (; m+4 <= ce; m += 4){
        int s0 = sh_src[0][m], s1 = sh_src[0][m+2];
        float a0 = sh_e[0][m*NH+hg], a1 = sh_e[0][(m+2)*NH+hg];
        float2 f0 = __half22float2(*(const __half2*)&hh16[(size_t)s0*HID + 2*l]);
        float2 f1 = __half22float2(*(const __half2*)&hh16[(size_t)s1*HID + 2*l]);
        aE0 = fmaf(f0.x, a0, aE0); aE1 = fmaf(f0.y, a0, aE1);
        aE0 = fmaf(f1.x, a1, aE0); aE1 = fmaf(f1.y, a1, aE1);
      }
      for (; m < ce; m += 2){
        int s0 = sh_src[0][m];
        float a0 = sh_e[0][m*NH+hg];
        float2 f0 = __half22float2(*(const __half2*)&hh16[(size_t)s0*HID + 2*l]);
        aE0 = fmaf(f0.x, a0, aE0); aE1 = fmaf(f0.y, a0, aE1);
      }
    }
    {
      int m = w;
      for (; m+4 <= ct; m += 4){
        int s0 = sh_src[1][m], s1 = sh_src[1][m+2];
        float a0 = sh_e[1][m*NH+hg], a1 = sh_e[1][(m+2)*NH+hg];
        float2 f0 = __half22float2(*(const __half2*)&hh16[(size_t)s0*HID + 2*l]);
        float2 f1 = __half22float2(*(const __half2*)&hh16[(size_t)s1*HID + 2*l]);
        aT0 = fmaf(f0.x, a0, aT0); aT1 = fmaf(f0.y, a0, aT1);
        aT0 = fmaf(f1.x, a1, aT0); aT1 = fmaf(f1.y, a1, aT1);
      }
      for (; m < ct; m += 2){
        int s0 = sh_src[1][m];
        float a0 = sh_e[1][m*NH+hg];
        float2 f0 = __half22float2(*(const __half2*)&hh16[(size_t)s0*HID + 2*l]);
        aT0 = fmaf(f0.x, a0, aT0); aT1 = fmaf(f0.y, a0, aT1);
      }
    }
    {
      int m = w;
      for (; m+4 <= cq; m += 4){
        int s0 = sh_src[2][m], s1 = sh_src[2][m+2];
        float a0 = sh_e[2][m*NH+hg], a1 = sh_e[2][(m+2)*NH+hg];
        float2 f0 = __half22float2(*(const __half2*)&hh16[(size_t)s0*HID + 2*l]);
        float2 f1 = __half22float2(*(const __half2*)&hh16[(size_t)s1*HID + 2*l]);
        aQ0 = fmaf(f0.x, a0, aQ0); aQ1 = fmaf(f0.y, a0, aQ1);
        aQ0 = fmaf(f1.x, a1, aQ0); aQ1 = fmaf(f1.y, a1, aQ1);
      }
      for (; m < cq; m += 2){
        int s0 = sh_src[2][m];
        float a0 = sh_e[2][m*NH+hg];
        float2 f0 = __half22float2(*(const __half2*)&hh16[(size_t)s0*HID + 2*l]);
        aQ0 = fmaf(f0.x, a0, aQ0); aQ1 = fmaf(f0.y, a0, aQ1);
      }
    }
    __syncthreads();
  }
  // ---- tail: cross-wave combine (reuse sh_e as [3][2][128] buffer), divide, residual, ELU ----
  float* red = &sh_e[0][0];
  *(float2*)&red[(0*2+w)*128 + 2*l] = make_float2(aE0, aE1);
  *(float2*)&red[(1*2+w)*128 + 2*l] = make_float2(aT0, aT1);
  *(float2*)&red[(2*2+w)*128 + 2*l] = make_float2(aQ0, aQ1);
  __syncthreads();
  int ho = t >> 4;
  float outv = (red[t]       + red[128+t]) / (sh_s[ho]    + 1e-16f)
             + (red[256+t]   + red[384+t]) / (sh_s[8+ho]  + 1e-16f)
             + (red[512+t]   + red[640+t]) / (sh_s[16+ho] + 1e-16f);
  size_t oi = (size_t)n*HID + t;
  hout[oi] = eluf(hlr[oi] + outv);
}

// ---------------- pooling: sum + max per graph ----------------
__global__ __launch_bounds__(128) void k_pool(const float* __restrict__ h, const int* __restrict__ goff,
                                              float* __restrict__ gs, float* __restrict__ gmx){
  int g = blockIdx.x, t = threadIdx.x;
  int s = goff[g], e = goff[g+1];
  float sum = 0.f, mx = -INFINITY;
  for (int n=s; n<e; n++){
    float v = h[(size_t)n*HID+t];
    sum += v; mx = fmaxf(mx, v);
  }
  gs[(size_t)g*HID+t] = sum;
  gmx[(size_t)g*HID+t] = (s < e) ? mx : 0.f;
}

// ---------------- readout MLP: [257]->256->256->1, 8 graphs per block ----------------
#define GPB 8
#define MSTR 260
__global__ __launch_bounds__(256) void k_mlp(const float* __restrict__ gs, const float* __restrict__ gmx,
    const float* __restrict__ temps,
    const float* __restrict__ W1, const float* __restrict__ b1,
    const float* __restrict__ W2, const float* __restrict__ b2,
    const float* __restrict__ W3, const float* __restrict__ b3,
    float* __restrict__ out){
  __shared__ float mol[GPB][MSTR];
  __shared__ float hd[GPB][MSTR];
  int g0 = blockIdx.x*GPB, t = threadIdx.x;
  for (int i=t; i<GPB*HID; i+=256){
    int g=i>>7, d=i&127;
    mol[g][d]     = gs[(size_t)(g0+g)*HID+d];
    mol[g][128+d] = gmx[(size_t)(g0+g)*HID+d];
  }
  if (t < GPB){ mol[t][256]=temps[g0+t]; mol[t][257]=0.f; mol[t][258]=0.f; mol[t][259]=0.f; }
  __syncthreads();
  float acc[GPB];
  #pragma unroll
  for (int g=0;g<GPB;g++) acc[g]=b1[t];
  for (int k0=0;k0<256;k0+=4){
    float w0=W1[(size_t)(k0+0)*256+t], w1=W1[(size_t)(k0+1)*256+t];
    float w2=W1[(size_t)(k0+2)*256+t], w3=W1[(size_t)(k0+3)*256+t];
    #pragma unroll
    for (int g=0;g<GPB;g++){
      float4 m4 = *(const float4*)&mol[g][k0];
      acc[g] = fmaf(m4.x,w0, fmaf(m4.y,w1, fmaf(m4.z,w2, fmaf(m4.w,w3, acc[g]))));
    }
  }
  { float wl=W1[(size_t)256*256+t];
    #pragma unroll
    for (int g=0;g<GPB;g++) acc[g]=fmaf(mol[g][256],wl,acc[g]); }
  #pragma unroll
  for (int g=0;g<GPB;g++) hd[g][t]=eluf(acc[g]);
  __syncthreads();
  #pragma unroll
  for (int g=0;g<GPB;g++) acc[g]=b2[t];
  for (int k0=0;k0<256;k0+=4){
    float w0=W2[(size_t)(k0+0)*256+t], w1=W2[(size_t)(k0+1)*256+t];
    float w2=W2[(size_t)(k0+2)*256+t], w3=W2[(size_t)(k0+3)*256+t];
    #pragma unroll
    for (int g=0;g<GPB;g++){
      float4 h4 = *(const float4*)&hd[g][k0];
      acc[g] = fmaf(h4.x,w0, fmaf(h4.y,w1, fmaf(h4.z,w2, fmaf(h4.w,w3, acc[g]))));
    }
  }
  float w3v = W3[t];
  #pragma unroll
  for (int g=0;g<GPB;g++) mol[g][t] = eluf(acc[g])*w3v;   // mol reused as reduction buffer
  __syncthreads();
  int g = t >> 5, j = t & 31;
  float s = 0.f;
  for (int i=j; i<256; i+=32) s += mol[g][i];
  #pragma unroll
  for (int d=16; d>0; d>>=1) s += __shfl_down(s, d, 32);
  if (j == 0) out[g0+g] = s + b3[0];
}

extern "C" void kernel_launch(void* const* d_in, const int* in_sizes, int n_in,
                              void* d_out, int out_size, void* d_ws, size_t ws_size,
                              hipStream_t stream){
  const float* x         = (const float*)d_in[0];
  const float* pos       = (const float*)d_in[1];
  const float* edge_attr = (const float*)d_in[2];
  const float* temps     = (const float*)d_in[3];
  const int*   ei        = (const int*)d_in[4];
  const int*   ti        = (const int*)d_in[5];
  const int*   qi        = (const int*)d_in[6];
  const int*   batch     = (const int*)d_in[7];
  const float* W         = (const float*)d_in[8];
  const float* a_e       = (const float*)d_in[9];
  const float* a_t       = (const float*)d_in[10];
  const float* a_q       = (const float*)d_in[11];
  const float* We        = (const float*)d_in[12];
  const float* W1        = (const float*)d_in[13];
  const float* b1        = (const float*)d_in[14];
  const float* W2        = (const float*)d_in[15];
  const float* b2        = (const float*)d_in[16];
  const float* W3        = (const float*)d_in[17];
  const float* b3        = (const float*)d_in[18];
  float* out = (float*)d_out;

  char* base = (char*)d_ws; size_t woff = 0;
  auto alloc = [&](size_t bytes)->void*{
    void* p = base + woff;
    woff = (woff + bytes + 255) & ~(size_t)255;
    return p;
  };
  float*  hbuf   = (float*)alloc((size_t)NN*HID*4);
  float*  hl     = (float*)alloc((size_t)NN*HID*4);
  __half* hl16   = (__half*)alloc((size_t)NN*HID*2);
  float*  qa_e   = (float*)alloc((size_t)NN*NH*4);
  float*  ka_e   = (float*)alloc((size_t)NN*NH*4);
  float*  qa_t   = (float*)alloc((size_t)NN*NH*4);
  float*  ka_t   = (float*)alloc((size_t)NN*NH*4);
  float*  qa_q   = (float*)alloc((size_t)NN*NH*4);
  float*  ka_q   = (float*)alloc((size_t)NN*NH*4);
  int*    csrc_e = (int*)alloc((size_t)EE*4);
  int*    csrc_t = (int*)alloc((size_t)TT*4);
  int*    csrc_q = (int*)alloc((size_t)QQ*4);
  float*  cg_e   = (float*)alloc((size_t)EE*4);
  float*  cg_t   = (float*)alloc((size_t)TT*4);
  float*  cg_q   = (float*)alloc((size_t)QQ*4);
  float*  biasP  = (float*)alloc((size_t)EE*NH*4);
  int*    epos_e = (int*)alloc((size_t)EE*4);
  float*  gs     = (float*)alloc((size_t)GG*HID*4);
  float*  gmx    = (float*)alloc((size_t)GG*HID*4);
  int*    cnt    = (int*)alloc((size_t)3*NN*4);
  int*    off_e  = (int*)alloc((size_t)(NN+1)*4);
  int*    off_t  = (int*)alloc((size_t)(NN+1)*4);
  int*    off_q  = (int*)alloc((size_t)(NN+1)*4);
  int*    cur_e  = (int*)alloc((size_t)NN*4);
  int*    cur_t  = (int*)alloc((size_t)NN*4);
  int*    cur_q  = (int*)alloc((size_t)NN*4);
  int*    goff   = (int*)alloc((size_t)(GG+1)*4);

  // ---- CSR build + geometry ----
  hipMemsetAsync(cnt, 0, (size_t)3*NN*4, stream);
  int tot = EE+TT+QQ;
  k_count3<<<(tot+255)/256,256,0,stream>>>(ei, ti, qi, cnt);
  k_scan4<<<4,1024,0,stream>>>(cnt, off_e, off_t, off_q, cur_e, cur_t, cur_q, batch, goff);
  k_fillgeom<<<(tot+255)/256,256,0,stream>>>(pos, ei, ti, qi, cur_e, cur_t, cur_q,
                                             csrc_e, csrc_t, csrc_q, cg_e, cg_t, cg_q, epos_e);

  // ---- layers ----
  for (int l=0; l<3; l++){
    const float* hin = (l==0) ? x : hbuf;
    k_gemm<<<NN/GR,128,0,stream>>>(hin, W + (size_t)l*HID*HID, hl, hl16);
    k_projbias<<<(NN*NH+EE+255)/256,256,0,stream>>>(hl, a_e+l*264, a_t+l*264, a_q+l*264,
                                                    edge_attr, We + l*DH*NH, epos_e,
                                                    qa_e, ka_e, qa_t, ka_t, qa_q, ka_q, biasP);
    k_hop3<<<NN,128,0,stream>>>(off_e, off_t, off_q, csrc_e, csrc_t, csrc_q,
                                cg_e, cg_t, cg_q, biasP,
                                qa_e, ka_e, qa_t, ka_t, qa_q, ka_q,
                                a_e+l*264, a_t+l*264, a_q+l*264,
                                hl16, hl, hbuf);
  }

  // ---- readout ----
  k_pool<<<GG,128,0,stream>>>(hbuf, goff, gs, gmx);
  k_mlp<<<GG/GPB,256,0,stream>>>(gs, gmx, temps, W1, b1, W2, b2, W3, b3, out);
}